// Round 4
// baseline (1125.768 us; speedup 1.0000x reference)
//
#include <hip/hip_runtime.h>
#include <cmath>

#define SLOPE 0.2f
#define EPSV 1e-5f

// ======================= CSR build (once per call) =======================
__global__ __launch_bounds__(256) void deg_init_kernel(int* __restrict__ deg, int n) {
    int i = blockIdx.x * 256 + threadIdx.x;
    if (i <= n) deg[i] = (i < n) ? 1 : 0;  // self-loop counts; virtual elem n = 0
}

__global__ __launch_bounds__(256) void hist_kernel(const int* __restrict__ dst, int E,
                                                   int* __restrict__ deg) {
    int stride = gridDim.x * 256;
    for (int e = blockIdx.x * 256 + threadIdx.x; e < E; e += stride)
        atomicAdd(&deg[dst[e]], 1);
}

__global__ __launch_bounds__(256) void scan_block_kernel(const int* __restrict__ deg,
                                                         int* __restrict__ row,
                                                         int* __restrict__ partials, int n1) {
    __shared__ int s[256];
    int t = threadIdx.x;
    int i = blockIdx.x * 256 + t;
    int v = (i < n1) ? deg[i] : 0;
    s[t] = v;
    __syncthreads();
    for (int off = 1; off < 256; off <<= 1) {
        int x = (t >= off) ? s[t - off] : 0;
        __syncthreads();
        s[t] += x;
        __syncthreads();
    }
    if (i < n1) row[i] = s[t] - v;  // exclusive (block-local)
    if (t == 255) partials[blockIdx.x] = s[255];
}

__global__ __launch_bounds__(1024) void scan_top_kernel(int* __restrict__ partials, int nb) {
    __shared__ int s[1024];
    int t = threadIdx.x;
    int v = (t < nb) ? partials[t] : 0;
    s[t] = v;
    __syncthreads();
    for (int off = 1; off < 1024; off <<= 1) {
        int x = (t >= off) ? s[t - off] : 0;
        __syncthreads();
        s[t] += x;
        __syncthreads();
    }
    if (t < nb) partials[t] = s[t] - v;  // exclusive block offsets
}

__global__ __launch_bounds__(256) void scan_add_kernel(int* __restrict__ row,
                                                       const int* __restrict__ partials, int n1) {
    int i = blockIdx.x * 256 + threadIdx.x;
    if (i < n1) row[i] += partials[blockIdx.x];
}

__global__ __launch_bounds__(256) void fill_self_kernel(const int* __restrict__ row,
                                                        int* __restrict__ cursor,
                                                        int* __restrict__ csr, int n) {
    int i = blockIdx.x * 256 + threadIdx.x;
    if (i < n) {
        int p = row[i];
        csr[p] = i;  // self-loop first
        cursor[i] = p + 1;
    }
}

__global__ __launch_bounds__(256) void fill_edge_kernel(const int* __restrict__ src,
                                                        const int* __restrict__ dst, int E,
                                                        int* __restrict__ cursor,
                                                        int* __restrict__ csr) {
    int stride = gridDim.x * 256;
    for (int e = blockIdx.x * 256 + threadIdx.x; e < E; e += stride) {
        int p = atomicAdd(&cursor[dst[e]], 1);
        csr[p] = src[e];
    }
}

// ========== layer-1 GEMM (256->64) + scores: split-K, W in registers =========
// Block = 4 waves. Wave w holds W[64w+k][lane] (k=0..63) in 64 VGPRs and
// computes a 64-wide partial over its K-quarter for 4 nodes; 4KB LDS reduce.
__global__ __launch_bounds__(256) void gemm_scores256_kernel(
    const float* __restrict__ X, const float* __restrict__ W,
    const float* __restrict__ a_s, const float* __restrict__ a_d,
    float* __restrict__ H, float* __restrict__ s_src, float* __restrict__ s_dst, int n) {
    __shared__ float part[4 * 4 * 64];  // [node_g][wave][lane]
    const int lane = threadIdx.x & 63;
    const int wv = threadIdx.x >> 6;
    float wcol[64];
#pragma unroll
    for (int k = 0; k < 64; ++k) wcol[k] = W[(wv * 64 + k) * 64 + lane];
    const float as_l = a_s[lane];
    const float ad_l = a_d[lane];

    for (int base = blockIdx.x * 4; base < n; base += gridDim.x * 4) {
#pragma unroll
        for (int g = 0; g < 4; ++g) {
            const int node = base + g;
            float acc = 0.f;
            if (node < n) {
                const float4* xr =
                    reinterpret_cast<const float4*>(X + (size_t)node * 256 + wv * 64);
#pragma unroll
                for (int k4 = 0; k4 < 16; ++k4) {
                    float4 x4 = xr[k4];
                    acc = fmaf(x4.x, wcol[4 * k4 + 0],
                          fmaf(x4.y, wcol[4 * k4 + 1],
                          fmaf(x4.z, wcol[4 * k4 + 2],
                          fmaf(x4.w, wcol[4 * k4 + 3], acc))));
                }
            }
            part[(g * 4 + wv) * 64 + lane] = acc;
        }
        __syncthreads();
        const int node = base + wv;
        if (node < n) {
            float h = part[(wv * 4 + 0) * 64 + lane] + part[(wv * 4 + 1) * 64 + lane] +
                      part[(wv * 4 + 2) * 64 + lane] + part[(wv * 4 + 3) * 64 + lane];
            H[(size_t)node * 64 + lane] = h;
            float ps = h * as_l, pd = h * ad_l;
#pragma unroll
            for (int off = 32; off; off >>= 1) {
                ps += __shfl_xor(ps, off);
                pd += __shfl_xor(pd, off);
            }
            if (lane == 0) {
                s_src[node] = ps;
                s_dst[node] = pd;
            }
        }
        __syncthreads();
    }
}

// ========== layer-2/3 GEMM (64->64) + scores: W in registers, no LDS =========
__global__ __launch_bounds__(256) void gemm_scores64_kernel(
    const float* __restrict__ X, const float* __restrict__ W,
    const float* __restrict__ a_s, const float* __restrict__ a_d,
    float* __restrict__ H, float* __restrict__ s_src, float* __restrict__ s_dst, int n) {
    const int lane = threadIdx.x & 63;
    const int wv = threadIdx.x >> 6;
    float wcol[64];
#pragma unroll
    for (int k = 0; k < 64; ++k) wcol[k] = W[k * 64 + lane];
    const float as_l = a_s[lane];
    const float ad_l = a_d[lane];
    const int wid = blockIdx.x * 4 + wv;
    const int nw = gridDim.x * 4;

    for (int base = wid * 4; base < n; base += nw * 4) {
        if (base + 4 <= n) {
            const float4* x0 = reinterpret_cast<const float4*>(X + (size_t)(base + 0) * 64);
            const float4* x1 = reinterpret_cast<const float4*>(X + (size_t)(base + 1) * 64);
            const float4* x2 = reinterpret_cast<const float4*>(X + (size_t)(base + 2) * 64);
            const float4* x3 = reinterpret_cast<const float4*>(X + (size_t)(base + 3) * 64);
            float a0 = 0.f, a1 = 0.f, a2 = 0.f, a3 = 0.f;
#pragma unroll
            for (int k4 = 0; k4 < 16; ++k4) {
                float4 xa = x0[k4], xb = x1[k4], xc = x2[k4], xd = x3[k4];
                float w0 = wcol[4 * k4 + 0], w1 = wcol[4 * k4 + 1];
                float w2 = wcol[4 * k4 + 2], w3 = wcol[4 * k4 + 3];
                a0 = fmaf(xa.x, w0, fmaf(xa.y, w1, fmaf(xa.z, w2, fmaf(xa.w, w3, a0))));
                a1 = fmaf(xb.x, w0, fmaf(xb.y, w1, fmaf(xb.z, w2, fmaf(xb.w, w3, a1))));
                a2 = fmaf(xc.x, w0, fmaf(xc.y, w1, fmaf(xc.z, w2, fmaf(xc.w, w3, a2))));
                a3 = fmaf(xd.x, w0, fmaf(xd.y, w1, fmaf(xd.z, w2, fmaf(xd.w, w3, a3))));
            }
            H[(size_t)(base + 0) * 64 + lane] = a0;
            H[(size_t)(base + 1) * 64 + lane] = a1;
            H[(size_t)(base + 2) * 64 + lane] = a2;
            H[(size_t)(base + 3) * 64 + lane] = a3;
            float p0s = a0 * as_l, p0d = a0 * ad_l;
            float p1s = a1 * as_l, p1d = a1 * ad_l;
            float p2s = a2 * as_l, p2d = a2 * ad_l;
            float p3s = a3 * as_l, p3d = a3 * ad_l;
#pragma unroll
            for (int off = 32; off; off >>= 1) {
                p0s += __shfl_xor(p0s, off); p0d += __shfl_xor(p0d, off);
                p1s += __shfl_xor(p1s, off); p1d += __shfl_xor(p1d, off);
                p2s += __shfl_xor(p2s, off); p2d += __shfl_xor(p2d, off);
                p3s += __shfl_xor(p3s, off); p3d += __shfl_xor(p3d, off);
            }
            if (lane == 0) {
                s_src[base + 0] = p0s; s_dst[base + 0] = p0d;
                s_src[base + 1] = p1s; s_dst[base + 1] = p1d;
                s_src[base + 2] = p2s; s_dst[base + 2] = p2d;
                s_src[base + 3] = p3s; s_dst[base + 3] = p3d;
            }
        } else {
            for (int node = base; node < n; ++node) {
                const float4* xr = reinterpret_cast<const float4*>(X + (size_t)node * 64);
                float acc = 0.f;
#pragma unroll
                for (int k4 = 0; k4 < 16; ++k4) {
                    float4 x4 = xr[k4];
                    acc = fmaf(x4.x, wcol[4 * k4 + 0],
                          fmaf(x4.y, wcol[4 * k4 + 1],
                          fmaf(x4.z, wcol[4 * k4 + 2],
                          fmaf(x4.w, wcol[4 * k4 + 3], acc))));
                }
                H[(size_t)node * 64 + lane] = acc;
                float ps = acc * as_l, pd = acc * ad_l;
#pragma unroll
                for (int off = 32; off; off >>= 1) {
                    ps += __shfl_xor(ps, off);
                    pd += __shfl_xor(pd, off);
                }
                if (lane == 0) { s_src[node] = ps; s_dst[node] = pd; }
            }
        }
    }
}

// =========== scores directly from 64-dim x (layer 4, project-after) ==========
__global__ __launch_bounds__(256) void scores_x_kernel(
    const float* __restrict__ X, const float* __restrict__ Was,
    const float* __restrict__ Wad, float* __restrict__ s_src,
    float* __restrict__ s_dst, int n) {
    const int lane = threadIdx.x & 63;
    const int node = (blockIdx.x * 256 + threadIdx.x) >> 6;
    if (node >= n) return;
    float x = X[(size_t)node * 64 + lane];
    float ps = x * Was[lane];
    float pd = x * Wad[lane];
#pragma unroll
    for (int off = 32; off; off >>= 1) {
        ps += __shfl_xor(ps, off);
        pd += __shfl_xor(pd, off);
    }
    if (lane == 0) {
        s_src[node] = ps;
        s_dst[node] = pd;
    }
}

// ================== Wa = W @ a  (tiny, 1 block, 128 threads) =================
__global__ __launch_bounds__(128) void wa_kernel(const float* __restrict__ W /*64x256*/,
                                                 const float* __restrict__ a_s,
                                                 const float* __restrict__ a_d,
                                                 float* __restrict__ Was,
                                                 float* __restrict__ Wad) {
    int t = threadIdx.x;
    int k = t & 63;
    const float* a = (t < 64) ? a_s : a_d;
    float* o = (t < 64) ? Was : Wad;
    const float4* wr = reinterpret_cast<const float4*>(W + (size_t)k * 256);
    const float4* a4 = reinterpret_cast<const float4*>(a);
    float acc = 0.f;
#pragma unroll
    for (int j = 0; j < 64; ++j) {
        float4 w = wr[j];
        float4 av = a4[j];
        acc = fmaf(w.x, av.x, acc);
        acc = fmaf(w.y, av.y, acc);
        acc = fmaf(w.z, av.z, acc);
        acc = fmaf(w.w, av.w, acc);
    }
    o[k] = acc;
}

// ======== fused softmax + aggregate: one wave per dst node (dout=64) =========
// MODE 0: out = BN(relu(acc + bi));  MODE 1: out = acc (raw, for project-after)
template <int MODE>
__global__ __launch_bounds__(256) void gather_kernel(
    const int* __restrict__ row, const int* __restrict__ csr,
    const float* __restrict__ s_src, const float* __restrict__ s_dst,
    const float* __restrict__ H, const float* __restrict__ bi,
    const float* __restrict__ g, const float* __restrict__ be,
    float* __restrict__ Out, int n) {
    const int lane = threadIdx.x & 63;
    const int node = (blockIdx.x * 256 + threadIdx.x) >> 6;
    if (node >= n) return;
    const int beg = row[node];
    const int end = row[node + 1];
    const int deg = end - beg;
    const float sdd = s_dst[node];

    // --- pass 1: online max+denominator (lane-parallel), cache first 64 ---
    const int e0 = beg + lane;
    int c0 = 0;
    float v0 = -1e30f;
    bool has0 = (e0 < end);
    if (has0) {
        c0 = csr[e0];
        float t = s_src[c0] + sdd;
        v0 = t >= 0.f ? t : SLOPE * t;
    }
    float m = v0;
    float dl = has0 ? 1.f : 0.f;
    for (int e = e0 + 64; e < end; e += 64) {
        int s = csr[e];
        float t = s_src[s] + sdd;
        t = t >= 0.f ? t : SLOPE * t;
        float nm = fmaxf(m, t);
        dl = dl * __expf(m - nm) + __expf(t - nm);
        m = nm;
    }
    float M = m;
#pragma unroll
    for (int off = 32; off; off >>= 1) M = fmaxf(M, __shfl_xor(M, off));
    dl *= __expf(m - M);
#pragma unroll
    for (int off = 32; off; off >>= 1) dl += __shfl_xor(dl, off);
    const float invden = 1.f / (dl + 1e-16f);
    const float p0 = has0 ? __expf(v0 - M) : 0.f;

    // --- pass 2: weighted accumulation, lane = channel ---
    float acc = 0.f;
    const int nf = deg < 64 ? deg : 64;
    int k = 0;
    for (; k + 8 <= nf; k += 8) {
        int s0 = __shfl(c0, k + 0), s1 = __shfl(c0, k + 1);
        int s2 = __shfl(c0, k + 2), s3 = __shfl(c0, k + 3);
        int s4 = __shfl(c0, k + 4), s5 = __shfl(c0, k + 5);
        int s6 = __shfl(c0, k + 6), s7 = __shfl(c0, k + 7);
        float a0 = __shfl(p0, k + 0), a1 = __shfl(p0, k + 1);
        float a2 = __shfl(p0, k + 2), a3 = __shfl(p0, k + 3);
        float a4 = __shfl(p0, k + 4), a5 = __shfl(p0, k + 5);
        float a6 = __shfl(p0, k + 6), a7 = __shfl(p0, k + 7);
        float h0 = H[(size_t)s0 * 64 + lane], h1 = H[(size_t)s1 * 64 + lane];
        float h2 = H[(size_t)s2 * 64 + lane], h3 = H[(size_t)s3 * 64 + lane];
        float h4 = H[(size_t)s4 * 64 + lane], h5 = H[(size_t)s5 * 64 + lane];
        float h6 = H[(size_t)s6 * 64 + lane], h7 = H[(size_t)s7 * 64 + lane];
        acc = fmaf(a0, h0, acc); acc = fmaf(a1, h1, acc);
        acc = fmaf(a2, h2, acc); acc = fmaf(a3, h3, acc);
        acc = fmaf(a4, h4, acc); acc = fmaf(a5, h5, acc);
        acc = fmaf(a6, h6, acc); acc = fmaf(a7, h7, acc);
    }
    for (; k < nf; ++k) {
        int s = __shfl(c0, k);
        float a = __shfl(p0, k);
        acc = fmaf(a, H[(size_t)s * 64 + lane], acc);
    }
    for (int e = beg + 64; e < end; ++e) {  // rare overflow (deg > 64)
        int s = csr[e];
        float t = s_src[s] + sdd;
        t = t >= 0.f ? t : SLOPE * t;
        acc = fmaf(__expf(t - M), H[(size_t)s * 64 + lane], acc);
    }
    acc *= invden;

    float o;
    if (MODE == 0) {
        o = fmaxf(acc + bi[lane], 0.f) * (g[lane] * rsqrtf(1.f + EPSV)) + be[lane];
    } else {
        o = acc;
    }
    Out[(size_t)node * 64 + lane] = o;
}

// ========= layer-4 projection: Out = relu(Agg @ W + b), 64 -> 256 ===========
__global__ __launch_bounds__(256) void gemm_out_kernel(const float* __restrict__ X,
                                                       const float* __restrict__ W,
                                                       const float* __restrict__ bi,
                                                       float* __restrict__ Out, int n) {
    const int j = threadIdx.x;
    float wcol[64];
#pragma unroll
    for (int k = 0; k < 64; ++k) wcol[k] = W[k * 256 + j];
    const float bj = bi[j];
    for (int node = blockIdx.x; node < n; node += gridDim.x) {
        const float4* xr = reinterpret_cast<const float4*>(X + (size_t)node * 64);
        float acc = 0.f;
#pragma unroll
        for (int k4 = 0; k4 < 16; ++k4) {
            float4 x4 = xr[k4];
            acc = fmaf(x4.x, wcol[4 * k4 + 0],
                  fmaf(x4.y, wcol[4 * k4 + 1],
                  fmaf(x4.z, wcol[4 * k4 + 2],
                  fmaf(x4.w, wcol[4 * k4 + 3], acc))));
        }
        Out[(size_t)node * 256 + j] = fmaxf(acc + bj, 0.f);
    }
}

// ================================ launcher ===================================
extern "C" void kernel_launch(void* const* d_in, const int* in_sizes, int n_in,
                              void* d_out, int out_size, void* d_ws,
                              size_t ws_size, hipStream_t stream) {
    const float* feat = (const float*)d_in[0];
    const int* eidx = (const int*)d_in[1];
    const float* W[4] = {(const float*)d_in[2], (const float*)d_in[6],
                         (const float*)d_in[10], (const float*)d_in[14]};
    const float* As[4] = {(const float*)d_in[3], (const float*)d_in[7],
                          (const float*)d_in[11], (const float*)d_in[15]};
    const float* Ad[4] = {(const float*)d_in[4], (const float*)d_in[8],
                          (const float*)d_in[12], (const float*)d_in[16]};
    const float* Bi[4] = {(const float*)d_in[5], (const float*)d_in[9],
                          (const float*)d_in[13], (const float*)d_in[17]};
    const float* G[3] = {(const float*)d_in[18], (const float*)d_in[20],
                         (const float*)d_in[22]};
    const float* Be[3] = {(const float*)d_in[19], (const float*)d_in[21],
                          (const float*)d_in[23]};

    const int N = in_sizes[0] / 256;
    const int E = in_sizes[1] / 2;
    const int* srcA = eidx;
    const int* dstA = eidx + E;

    // ---------------- workspace layout (floats unless noted) ----------------
    float* h = (float*)d_ws;                       // N*64  (h, also layer-4 Agg)
    float* xA = h + (size_t)N * 64;                // N*64
    float* xB = xA + (size_t)N * 64;               // N*64
    float* s_src = xB + (size_t)N * 64;            // N
    float* s_dst = s_src + N;                      // N
    float* Was = s_dst + N;                        // 64
    float* Wad = Was + 64;                         // 64
    int* deg = (int*)(Wad + 64);                   // N+1
    int* row = deg + (N + 1);                      // N+1
    int* cursor = row + (N + 1);                   // N
    int* partials = cursor + N;                    // 1024
    int* csr = partials + 1024;                    // E+N

    const int n1 = N + 1;
    const int NB1 = (n1 + 255) / 256;
    const int node_grid = (N + 3) / 4;             // one wave per node
    (void)ws_size; (void)n_in; (void)out_size;

    // ---------------- build CSR (once; reused by all 4 layers) --------------
    deg_init_kernel<<<NB1, 256, 0, stream>>>(deg, N);
    hist_kernel<<<2048, 256, 0, stream>>>(dstA, E, deg);
    scan_block_kernel<<<NB1, 256, 0, stream>>>(deg, row, partials, n1);
    scan_top_kernel<<<1, 1024, 0, stream>>>(partials, NB1);
    scan_add_kernel<<<NB1, 256, 0, stream>>>(row, partials, n1);
    fill_self_kernel<<<NB1, 256, 0, stream>>>(row, cursor, csr, N);
    fill_edge_kernel<<<2048, 256, 0, stream>>>(srcA, dstA, E, cursor, csr);

    // ---------------- layer 1: 256 -> 64, BN -------------------------------
    gemm_scores256_kernel<<<1024, 256, 0, stream>>>(
        feat, W[0], As[0], Ad[0], h, s_src, s_dst, N);
    gather_kernel<0><<<node_grid, 256, 0, stream>>>(
        row, csr, s_src, s_dst, h, Bi[0], G[0], Be[0], xA, N);

    // ---------------- layer 2: 64 -> 64, BN --------------------------------
    gemm_scores64_kernel<<<1024, 256, 0, stream>>>(
        xA, W[1], As[1], Ad[1], h, s_src, s_dst, N);
    gather_kernel<0><<<node_grid, 256, 0, stream>>>(
        row, csr, s_src, s_dst, h, Bi[1], G[1], Be[1], xB, N);

    // ---------------- layer 3: 64 -> 64, BN --------------------------------
    gemm_scores64_kernel<<<1024, 256, 0, stream>>>(
        xB, W[2], As[2], Ad[2], h, s_src, s_dst, N);
    gather_kernel<0><<<node_grid, 256, 0, stream>>>(
        row, csr, s_src, s_dst, h, Bi[2], G[2], Be[2], xA, N);

    // ---------------- layer 4: aggregate in 64-dim, project after ----------
    wa_kernel<<<1, 128, 0, stream>>>(W[3], As[3], Ad[3], Was, Wad);
    scores_x_kernel<<<node_grid, 256, 0, stream>>>(xA, Was, Wad, s_src, s_dst, N);
    gather_kernel<1><<<node_grid, 256, 0, stream>>>(
        row, csr, s_src, s_dst, xA, nullptr, nullptr, nullptr, h, N);
    gemm_out_kernel<<<2048, 256, 0, stream>>>(h, W[3], Bi[3], (float*)d_out, N);
}